// Round 18
// baseline (251.101 us; speedup 1.0000x reference)
//
#include <hip/hip_runtime.h>

// ---------------------------------------------------------------------------
// Attention block (B=2, S=2048, DIM=2048, H=32, KVH=8, HD=64, causal, RoPE)
// prep (cvt x + 4 weight transposes) ; QKV GEMM (128^2 2-phase, LDS-shuffled
// full-line C-store) ; rope+vt ; flash attention (paired q-tiles, 8 waves,
// KV-split, static-max softmax, pipelined QK^T, hoisted V-reads, deferred
// row-sum merge) ; out GEMM (fp32) -> d_out
// ---------------------------------------------------------------------------

using u16   = unsigned short;
using u32   = unsigned int;
using f32x4 = __attribute__((ext_vector_type(4))) float;
using f32x16= __attribute__((ext_vector_type(16))) float;
using s16x8 = __attribute__((ext_vector_type(8))) short;
using b16x8 = __attribute__((ext_vector_type(8))) __bf16;
using u16x4 = __attribute__((ext_vector_type(4))) unsigned short;
using u16x8 = __attribute__((ext_vector_type(8))) unsigned short;
using u32x4 = __attribute__((ext_vector_type(4))) u32;

__device__ __forceinline__ u16 f2bf(float f) {
  u32 u = __builtin_bit_cast(u32, f);
  u = (u + 0x7fffu + ((u >> 16) & 1u)) >> 16;   // round-to-nearest-even
  return (u16)u;
}
__device__ __forceinline__ float bf2f(u32 lo16) {
  return __builtin_bit_cast(float, lo16 << 16);
}

__device__ __forceinline__ f32x4 mfma16(s16x8 a, s16x8 b, f32x4 c) {
  return __builtin_amdgcn_mfma_f32_16x16x32_bf16(
      __builtin_bit_cast(b16x8, a), __builtin_bit_cast(b16x8, b), c, 0, 0, 0);
}
__device__ __forceinline__ f32x16 mfma32(s16x8 a, s16x8 b, f32x16 c) {
  return __builtin_amdgcn_mfma_f32_32x32x16_bf16(
      __builtin_bit_cast(b16x8, a), __builtin_bit_cast(b16x8, b), c, 0, 0, 0);
}

__device__ __forceinline__ void gload_lds16(const void* g, void* l) {
  __builtin_amdgcn_global_load_lds(
      (const __attribute__((address_space(1))) void*)g,
      (__attribute__((address_space(3))) void*)l, 16, 0, 0);
}

__device__ __forceinline__ u32 cvtpk(float lo, float hi) {
  u32 r; asm("v_cvt_pk_bf16_f32 %0, %1, %2" : "=v"(r) : "v"(lo), "v"(hi));
  return r;
}

__device__ __forceinline__ float fexp2(float x) {
#if __has_builtin(__builtin_amdgcn_exp2f)
  return __builtin_amdgcn_exp2f(x);
#else
  return exp2f(x);
#endif
}

// ---------------------------------------------------------------------------
// prep: job-merged {cvt x -> bf16} + {transpose-cvt wq, wk, wv, wo}.
__global__ __launch_bounds__(256) void prep_kernel(
    const float* __restrict__ x,  const float* __restrict__ wq,
    const float* __restrict__ wk, const float* __restrict__ wv,
    const float* __restrict__ wo, u16* __restrict__ xb,
    u16* __restrict__ wqkvT, u16* __restrict__ woT) {
  __shared__ float t[32][33];
  int bid = blockIdx.x;
  if (bid < 8192) {                              // ---- cvt x (float4/thread)
    const int i = bid * 256 + threadIdx.x;       // < 2097152
    f32x4 v = *(const f32x4*)(x + (size_t)i * 4);
    u16x4 r;
#pragma unroll
    for (int j = 0; j < 4; ++j) r[j] = f2bf(v[j]);
    *(u16x4*)(xb + (size_t)i * 4) = r;
    return;
  }
  bid -= 8192;
  const float* src;  u16* dst;  int N, gx;
  if (bid < 4096)      { src = wq; dst = wqkvT;                          N = 2048; gx = 64; }
  else if (bid < 5120) { bid -= 4096; src = wk; dst = wqkvT + (size_t)2048 * 2048; N = 512; gx = 16; }
  else if (bid < 6144) { bid -= 5120; src = wv; dst = wqkvT + (size_t)2560 * 2048; N = 512; gx = 16; }
  else                 { bid -= 6144; src = wo; dst = woT;               N = 2048; gx = 64; }
  const int n0 = (bid % gx) * 32, k0 = (bid / gx) * 32;
  const int tx = threadIdx.x & 31, ty = threadIdx.x >> 5;
#pragma unroll
  for (int r = 0; r < 4; ++r)
    t[ty + 8 * r][tx] = src[(size_t)(k0 + ty + 8 * r) * N + n0 + tx];
  __syncthreads();
#pragma unroll
  for (int r = 0; r < 4; ++r)
    dst[(size_t)(n0 + ty + 8 * r) * 2048 + k0 + tx] = f2bf(t[tx][ty + 8 * r]);
}

// ---------------------------------------------------------------------------
// ropevt: job-merged {RoPE in-place on q,k cols} + {V transpose to VtG}.
__global__ __launch_bounds__(256) void ropevt_kernel(u16* __restrict__ qkv,
                                                     const float* __restrict__ cs,
                                                     const float* __restrict__ sn,
                                                     u16* __restrict__ VtG) {
  __shared__ u16 t[64][65];
  const int bid = blockIdx.x;
  if (bid < 20480) {                             // ---- RoPE
    const int m = bid & 4095;
    const int p = (bid >> 12) * 256 + threadIdx.x;   // 0..1279
    const int s = m & 2047;
    int col, d2;
    if (p < 1024) { col = 2 * p; d2 = p & 31; }
    else { int pk = p - 1024; col = 2048 + 2 * pk; d2 = pk & 31; }
    const float c = cs[s * 32 + d2], si = sn[s * 32 + d2];
    u32* addr = (u32*)&qkv[(size_t)m * 3072 + col];
    u32 v = *addr;
    float a = bf2f(v & 0xffffu), b = bf2f(v >> 16);
    float na = a * c - b * si;
    float nb = a * si + b * c;
    *addr = (u32)f2bf(na) | ((u32)f2bf(nb) << 16);
    return;
  }
  const int id2 = bid - 20480;                   // ---- V transpose
  const int s0 = (id2 & 31) * 64;
  const int bk = id2 >> 5;                       // b*8 + kvh
  const int b = bk >> 3, kvh = bk & 7;
  const int tx = threadIdx.x & 63, ty = threadIdx.x >> 6;  // ty 0..3
#pragma unroll
  for (int r = 0; r < 16; ++r)
    t[ty + 4 * r][tx] =
        qkv[(size_t)(b * 2048 + s0 + ty + 4 * r) * 3072 + 2560 + kvh * 64 + tx];
  __syncthreads();
#pragma unroll
  for (int r = 0; r < 16; ++r)
    VtG[(size_t)(bk * 64 + ty + 4 * r) * 2048 + s0 + tx] = t[tx][ty + 4 * r];
}

// ---------------------------------------------------------------------------
// 128x128 BK=32 2-phase GEMM: C[M,N] = A[M,K]*Bt[N,K]^T, bf16 or fp32 out.
// Epilogue routes C through the dead staging LDS -> full-line global stores.
template <bool BF16OUT>
__global__ __launch_bounds__(256) void gemm_bt(const u16* __restrict__ A,
                                               const u16* __restrict__ Bt,
                                               void* __restrict__ Cv,
                                               int M, int N, int K, int GX) {
  __shared__ u16 SM[2][2][128 * 32];             // [A/B][buf][tile] = 32 KB
  const int tid = threadIdx.x;
  const int wid = tid >> 6, lane = tid & 63;
  const int l15 = lane & 15, lq = lane >> 4;
  const int wr = wid >> 1, wc = wid & 1;
  const int cpx = gridDim.x >> 3;                 // gridDim.x % 8 == 0
  const int swz = (blockIdx.x & 7) * cpx + (blockIdx.x >> 3);
  const int m0 = (swz / GX) * 128, n0 = (swz % GX) * 128;

  const int srow16 = lane >> 2;
  const int k8 = (lane & 3) * 8;

  auto STAGE = [&](int bb, int kt) {
#pragma unroll
    for (int i = 0; i < 2; ++i) {
      const int r = wid * 2 + i;                  // 16-row region
      const int row = r * 16 + srow16;
      gload_lds16(A + (size_t)(m0 + row) * K + kt + k8, &SM[0][bb][r * 512]);
      gload_lds16(Bt + (size_t)(n0 + row) * K + kt + k8, &SM[1][bb][r * 512]);
    }
  };

  f32x4 acc[4][4] = {};
  STAGE(0, 0);
  __syncthreads();
  int cur = 0;
  for (int kt = 0; kt < K; kt += 32) {
    if (kt + 32 < K) STAGE(cur ^ 1, kt + 32);
    s16x8 af[4], bf[4];
#pragma unroll
    for (int i = 0; i < 4; ++i)
      af[i] = *(const s16x8*)&SM[0][cur][(wr * 64 + i * 16 + l15) * 32 + 8 * lq];
#pragma unroll
    for (int j = 0; j < 4; ++j)
      bf[j] = *(const s16x8*)&SM[1][cur][(wc * 64 + j * 16 + l15) * 32 + 8 * lq];
#pragma unroll
    for (int i = 0; i < 4; ++i)
#pragma unroll
      for (int j = 0; j < 4; ++j)
        acc[i][j] = mfma16(af[i], bf[j], acc[i][j]);
    __syncthreads();                              // drains next-tile loads too
    cur ^= 1;
  }

  if constexpr (BF16OUT) {
    u16* lds = &SM[0][0][0];                      // 16384 u16 = 32 KB
    u16* Cb = (u16*)Cv;
#pragma unroll
    for (int i = 0; i < 4; ++i)
#pragma unroll
      for (int j = 0; j < 4; ++j)
#pragma unroll
        for (int r = 0; r < 4; ++r)
          lds[(wr * 64 + i * 16 + 4 * lq + r) * 128 + wc * 64 + j * 16 + l15] =
              f2bf(acc[i][j][r]);
    __syncthreads();
#pragma unroll
    for (int k = 0; k < 8; ++k) {
      const int rowL = k * 16 + (tid >> 4);
      const int colL = (tid & 15) * 8;
      u16x8 v = *(const u16x8*)&lds[rowL * 128 + colL];
      *(u16x8*)(Cb + (size_t)(m0 + rowL) * N + n0 + colL) = v;
    }
  } else {
    float* lds = (float*)&SM[0][0][0];            // 8192 f32 = 32 KB
    float* Cf = (float*)Cv;
#pragma unroll
    for (int half = 0; half < 2; ++half) {
      if (wc == half) {
#pragma unroll
        for (int i = 0; i < 4; ++i)
#pragma unroll
          for (int j = 0; j < 4; ++j)
#pragma unroll
            for (int r = 0; r < 4; ++r)
              lds[(wr * 64 + i * 16 + 4 * lq + r) * 64 + j * 16 + l15] =
                  acc[i][j][r];
      }
      __syncthreads();
#pragma unroll
      for (int k = 0; k < 8; ++k) {
        const int rowL = k * 16 + (tid >> 4);
        const int colL = (tid & 15) * 4;
        f32x4 v = *(const f32x4*)&lds[rowL * 64 + colL];
        *(f32x4*)(Cf + (size_t)(m0 + rowL) * N + n0 + half * 64 + colL) = v;
      }
      __syncthreads();
    }
  }
}

// ---------------------------------------------------------------------------
// Flash attention: paired q-tiles {15-bx, bx} per block (17 steps constant),
// 8 waves in 2 groups (A: KV[0,qt+1), B: KV[qt+1,2qt+2)), separate LDS
// double-buffers. Static-max softmax (m=0), pipelined QK^T, V-fragment reads
// hoisted above softmax (latency covered by VALU), per-lane row-sum with a
// single cross-lane merge after the loop, depth-5 tree reduction.
__global__ __launch_bounds__(512, 4) void attn_kernel(const u16* __restrict__ qkv,
                                                      const u16* __restrict__ VtG,
                                                      u16* __restrict__ aout) {
  constexpr int QSTR = 3072;
  constexpr float SCL = 0.18033688011112042f;    // (1/8) * log2(e)
  const int bx = blockIdx.x;                     // 0..7
  const int bh = blockIdx.y;
  const int b = bh >> 5, h = bh & 31, kvh = h >> 2;
  const int tid = threadIdx.x;
  const int w = tid >> 6, g = w >> 2, wq = w & 3;  // group, wave-in-group
  const int l31 = tid & 31, hh = (tid >> 5) & 1;

  __shared__ u16 KV[2][2][2][4096];              // [group][K/V][buf]
  __shared__ float cml[128];                     // l partials (group B)

  const int u = tid & 255;
  const int srow = u >> 3, sslot = u & 7;
  const int sd8 = (sslot ^ (srow & 7)) * 8;      // pre-swizzled source slot
  const u16* kg = qkv + (size_t)(b * 2048 + srow) * QSTR + 2048 + kvh * 64 + sd8;
  const u16* vg = VtG + (size_t)((b * 8 + kvh) * 64 + srow) * 2048 + sd8;
  const int wg = u >> 6;                         // wave-in-group 0..3
  const int xsw = l31 & 7;                       // read-side row XOR

  auto STAGE = [&](int buf, int t) {             // t = global KV tile index
    const size_t ko = (size_t)t * 64 * QSTR;
    const size_t vo = (size_t)t * 64;
    gload_lds16(kg + ko, &KV[g][0][buf][wg * 512]);
    gload_lds16(kg + ko + (size_t)32 * QSTR, &KV[g][0][buf][2048 + wg * 512]);
    gload_lds16(vg + vo, &KV[g][1][buf][wg * 512]);
    gload_lds16(vg + vo + (size_t)32 * 2048, &KV[g][1][buf][2048 + wg * 512]);
  };

  float* cO = (float*)&KV[1][0][0][0];           // 8192 f32 = 32 KB, 64 slots

  auto process = [&](int qt) {
    const int h1 = qt + 1;                       // steps per group
    const int q_abs = qt * 128 + wq * 32 + l31;  // lane's q row (both groups)
    const u16* qrow = qkv + (size_t)(b * 2048 + q_abs) * QSTR + h * 64;
    s16x8 qf[4];
#pragma unroll
    for (int s = 0; s < 4; ++s) qf[s] = *(const s16x8*)(qrow + 16 * s + 8 * hh);

    f32x16 o0 = {}, o1 = {};                     // O^T partial: d 0..31/32..63
    float lrun = 0.f;                            // per-lane partial (hh half)
    f32x16 a0, a1;                               // current tile scores

    auto qkt = [&](const u16* Kb) {
      a0 = (f32x16){}; a1 = (f32x16){};
      __builtin_amdgcn_s_setprio(1);
#pragma unroll
      for (int s4 = 0; s4 < 4; ++s4) {
        const int cc = ((2 * s4 + hh) ^ xsw) * 8;
        s16x8 k0 = *(const s16x8*)(Kb + l31 * 64 + cc);
        s16x8 k1 = *(const s16x8*)(Kb + (32 + l31) * 64 + cc);
        a0 = mfma32(k0, qf[s4], a0);
        a1 = mfma32(k1, qf[s4], a1);
      }
      __builtin_amdgcn_s_setprio(0);
    };

    STAGE(0, g * h1);
    __syncthreads();                             // buf0 ready
    qkt(&KV[g][0][0][0]);                        // scores for step 0

    for (int s = 0; s < h1; ++s) {
      if (s + 1 < h1) STAGE((s + 1) & 1, g * h1 + s + 1);
      const int kv0 = (g * h1 + s) * 64;

      // ---- hoist V-fragment loads: buffer valid since step start, so issue
      // the 8 ds_read_b128 now and let softmax VALU cover their latency.
      const u16* Vb = &KV[g][1][s & 1][0];
      s16x8 vf0[4], vf1[4];
#pragma unroll
      for (int s4 = 0; s4 < 4; ++s4) {
        const int cc = ((2 * s4 + hh) ^ xsw) * 8;
        vf0[s4] = *(const s16x8*)(Vb + l31 * 64 + cc);
        vf1[s4] = *(const s16x8*)(Vb + (32 + l31) * 64 + cc);
      }

      // ---- causal mask (raw domain)
      if (kv0 + 63 > qt * 128 + wq * 32) {
#pragma unroll
        for (int r = 0; r < 16; ++r) {
          const int kva = kv0 + (r & 3) + 8 * (r >> 2) + 4 * hh;
          if (kva > q_abs) a0[r] = -3e38f;
          if (kva + 32 > q_abs) a1[r] = -3e38f;
        }
      }

      // ---- static-max softmax: p = exp2(score*SCL); depth-5 tree sum
      float t01[16];
#pragma unroll
      for (int r = 0; r < 16; ++r) {
        a0[r] = fexp2(a0[r] * SCL);
        a1[r] = fexp2(a1[r] * SCL);
        t01[r] = a0[r] + a1[r];
      }
#pragma unroll
      for (int st = 8; st >= 1; st >>= 1)
#pragma unroll
        for (int r = 0; r < st; ++r) t01[r] += t01[r + st];
      lrun += t01[0];                            // cross-lane merge deferred

      // ---- pack P^T B-fragments (cvt_pk + permlane32_swap)
      s16x8 pf[4];
#pragma unroll
      for (int s4 = 0; s4 < 4; ++s4) {
        const f32x16& ps = (s4 & 2) ? a1 : a0;
        const int g4 = (s4 & 1) * 8;
        u32 x  = cvtpk(ps[g4 + 0], ps[g4 + 1]);
        u32 x2 = cvtpk(ps[g4 + 2], ps[g4 + 3]);
        u32 y  = cvtpk(ps[g4 + 4], ps[g4 + 5]);
        u32 y2 = cvtpk(ps[g4 + 6], ps[g4 + 7]);
        asm("v_permlane32_swap_b32 %0, %1" : "+v"(x), "+v"(y));
        asm("v_permlane32_swap_b32 %0, %1" : "+v"(x2), "+v"(y2));
        u32x4 fr = {x, x2, y, y2};
        pf[s4] = __builtin_bit_cast(s16x8, fr);
      }

      // ---- PV: O^T += V^T * P^T (fragments already in registers)
      __builtin_amdgcn_s_setprio(1);
#pragma unroll
      for (int s4 = 0; s4 < 4; ++s4) {
        o0 = mfma32(vf0[s4], pf[s4], o0);
        o1 = mfma32(vf1[s4], pf[s4], o1);
      }
      __builtin_amdgcn_s_setprio(0);

      __syncthreads();                           // drains s+1 loads; frees bufs
      if (s + 1 < h1) qkt(&KV[g][0][(s + 1) & 1][0]);   // pipelined next QK^T
    }

    lrun += __shfl_xor(lrun, 32);                // single cross-lane merge

    // ---- combine (shared m=0 basis): B writes partials; A merges.
    const int idx = wq * 32 + l31;
    if (g == 1) {
#pragma unroll
      for (int r = 0; r < 16; ++r) {
        cO[(hh * 16 + r) * 128 + idx] = o0[r];
        cO[(32 + hh * 16 + r) * 128 + idx] = o1[r];
      }
      if (hh == 0) cml[idx] = lrun;
    }
    __syncthreads();
    if (g == 0) {
      const float inv = 1.f / (lrun + cml[idx]);
      u16* ob = aout + (size_t)(b * 2048 + q_abs) * 2048 + h * 64;
#pragma unroll
      for (int gg = 0; gg < 4; ++gg) {
        u16x4 w0, w1;
#pragma unroll
        for (int j = 0; j < 4; ++j) {
          const int r = 4 * gg + j;
          w0[j] = f2bf((o0[r] + cO[(hh * 16 + r) * 128 + idx]) * inv);
          w1[j] = f2bf((o1[r] + cO[(32 + hh * 16 + r) * 128 + idx]) * inv);
        }
        *(u16x4*)(ob + 8 * gg + 4 * hh) = w0;
        *(u16x4*)(ob + 32 + 8 * gg + 4 * hh) = w1;
      }
    }
    __syncthreads();                             // scratch freed before reuse
  };

  process(15 - bx);   // heavy q-tile: 16-bx steps
  process(bx);        // light q-tile: bx+1 steps -> 17 steps per block
}

// ---------------------------------------------------------------------------
extern "C" void kernel_launch(void* const* d_in, const int* in_sizes, int n_in,
                              void* d_out, int out_size, void* d_ws, size_t ws_size,
                              hipStream_t stream) {
  const float* x    = (const float*)d_in[0];
  const float* wq   = (const float*)d_in[1];
  const float* wk   = (const float*)d_in[2];
  const float* wv   = (const float*)d_in[3];
  const float* wo   = (const float*)d_in[4];
  const float* cosT = (const float*)d_in[5];
  const float* sinT = (const float*)d_in[6];
  float* out = (float*)d_out;

  const size_t SZ_XB   = (size_t)4096 * 2048 * 2;
  const size_t SZ_WQKV = (size_t)3072 * 2048 * 2;
  const size_t SZ_WO   = (size_t)2048 * 2048 * 2;
  const size_t SZ_QKV  = (size_t)4096 * 3072 * 2;
  const size_t SZ_ATT  = (size_t)4096 * 2048 * 2;
  if (ws_size < SZ_XB + SZ_WQKV + SZ_WO + SZ_QKV + SZ_ATT) return;

  char* p = (char*)d_ws;
  u16* xb    = (u16*)p; p += SZ_XB;
  u16* wqkvT = (u16*)p; p += SZ_WQKV;
  u16* woT   = (u16*)p; p += SZ_WO;
  u16* qkv   = (u16*)p; p += SZ_QKV;
  u16* attn  = (u16*)p; p += SZ_ATT;
  u16* VtG   = xb;   // xb is dead after the QKV GEMM; ropevt runs after it

  prep_kernel<<<18432, 256, 0, stream>>>(x, wq, wk, wv, wo, xb, wqkvT, woT);
  gemm_bt<true><<<768, 256, 0, stream>>>(xb, wqkvT, qkv, 4096, 3072, 2048, 24);
  ropevt_kernel<<<20992, 256, 0, stream>>>(qkv, cosT, sinT, VtG);
  attn_kernel<<<dim3(8, 64), 512, 0, stream>>>(qkv, VtG, attn);
  gemm_bt<false><<<512, 256, 0, stream>>>(attn, woT, out, 4096, 2048, 2048, 16);
}

// Round 19
// 195.516 us; speedup vs baseline: 1.2843x; 1.2843x over previous
//
#include <hip/hip_runtime.h>

// ---------------------------------------------------------------------------
// Attention block (B=2, S=2048, DIM=2048, H=32, KVH=8, HD=64, causal, RoPE)
// prep (cvt x + 4 weight transposes) ; QKV GEMM (128^2 2-phase, LDS-shuffled
// full-line C-store) ; rope+vt ; flash attention (paired q-tiles, 8 waves,
// KV-split, static-max softmax, pipelined QK^T, deferred row-sum merge) ;
// out GEMM (fp32) -> d_out
// ---------------------------------------------------------------------------

using u16   = unsigned short;
using u32   = unsigned int;
using f32x4 = __attribute__((ext_vector_type(4))) float;
using f32x16= __attribute__((ext_vector_type(16))) float;
using s16x8 = __attribute__((ext_vector_type(8))) short;
using b16x8 = __attribute__((ext_vector_type(8))) __bf16;
using u16x4 = __attribute__((ext_vector_type(4))) unsigned short;
using u16x8 = __attribute__((ext_vector_type(8))) unsigned short;
using u32x4 = __attribute__((ext_vector_type(4))) u32;

__device__ __forceinline__ u16 f2bf(float f) {
  u32 u = __builtin_bit_cast(u32, f);
  u = (u + 0x7fffu + ((u >> 16) & 1u)) >> 16;   // round-to-nearest-even
  return (u16)u;
}
__device__ __forceinline__ float bf2f(u32 lo16) {
  return __builtin_bit_cast(float, lo16 << 16);
}

__device__ __forceinline__ f32x4 mfma16(s16x8 a, s16x8 b, f32x4 c) {
  return __builtin_amdgcn_mfma_f32_16x16x32_bf16(
      __builtin_bit_cast(b16x8, a), __builtin_bit_cast(b16x8, b), c, 0, 0, 0);
}
__device__ __forceinline__ f32x16 mfma32(s16x8 a, s16x8 b, f32x16 c) {
  return __builtin_amdgcn_mfma_f32_32x32x16_bf16(
      __builtin_bit_cast(b16x8, a), __builtin_bit_cast(b16x8, b), c, 0, 0, 0);
}

__device__ __forceinline__ void gload_lds16(const void* g, void* l) {
  __builtin_amdgcn_global_load_lds(
      (const __attribute__((address_space(1))) void*)g,
      (__attribute__((address_space(3))) void*)l, 16, 0, 0);
}

__device__ __forceinline__ u32 cvtpk(float lo, float hi) {
  u32 r; asm("v_cvt_pk_bf16_f32 %0, %1, %2" : "=v"(r) : "v"(lo), "v"(hi));
  return r;
}

__device__ __forceinline__ float fexp2(float x) {
#if __has_builtin(__builtin_amdgcn_exp2f)
  return __builtin_amdgcn_exp2f(x);
#else
  return exp2f(x);
#endif
}

// ---------------------------------------------------------------------------
// prep: job-merged {cvt x -> bf16} + {transpose-cvt wq, wk, wv, wo}.
__global__ __launch_bounds__(256) void prep_kernel(
    const float* __restrict__ x,  const float* __restrict__ wq,
    const float* __restrict__ wk, const float* __restrict__ wv,
    const float* __restrict__ wo, u16* __restrict__ xb,
    u16* __restrict__ wqkvT, u16* __restrict__ woT) {
  __shared__ float t[32][33];
  int bid = blockIdx.x;
  if (bid < 8192) {                              // ---- cvt x (float4/thread)
    const int i = bid * 256 + threadIdx.x;       // < 2097152
    f32x4 v = *(const f32x4*)(x + (size_t)i * 4);
    u16x4 r;
#pragma unroll
    for (int j = 0; j < 4; ++j) r[j] = f2bf(v[j]);
    *(u16x4*)(xb + (size_t)i * 4) = r;
    return;
  }
  bid -= 8192;
  const float* src;  u16* dst;  int N, gx;
  if (bid < 4096)      { src = wq; dst = wqkvT;                          N = 2048; gx = 64; }
  else if (bid < 5120) { bid -= 4096; src = wk; dst = wqkvT + (size_t)2048 * 2048; N = 512; gx = 16; }
  else if (bid < 6144) { bid -= 5120; src = wv; dst = wqkvT + (size_t)2560 * 2048; N = 512; gx = 16; }
  else                 { bid -= 6144; src = wo; dst = woT;               N = 2048; gx = 64; }
  const int n0 = (bid % gx) * 32, k0 = (bid / gx) * 32;
  const int tx = threadIdx.x & 31, ty = threadIdx.x >> 5;
#pragma unroll
  for (int r = 0; r < 4; ++r)
    t[ty + 8 * r][tx] = src[(size_t)(k0 + ty + 8 * r) * N + n0 + tx];
  __syncthreads();
#pragma unroll
  for (int r = 0; r < 4; ++r)
    dst[(size_t)(n0 + ty + 8 * r) * 2048 + k0 + tx] = f2bf(t[tx][ty + 8 * r]);
}

// ---------------------------------------------------------------------------
// ropevt: job-merged {RoPE in-place on q,k cols} + {V transpose to VtG}.
__global__ __launch_bounds__(256) void ropevt_kernel(u16* __restrict__ qkv,
                                                     const float* __restrict__ cs,
                                                     const float* __restrict__ sn,
                                                     u16* __restrict__ VtG) {
  __shared__ u16 t[64][65];
  const int bid = blockIdx.x;
  if (bid < 20480) {                             // ---- RoPE
    const int m = bid & 4095;
    const int p = (bid >> 12) * 256 + threadIdx.x;   // 0..1279
    const int s = m & 2047;
    int col, d2;
    if (p < 1024) { col = 2 * p; d2 = p & 31; }
    else { int pk = p - 1024; col = 2048 + 2 * pk; d2 = pk & 31; }
    const float c = cs[s * 32 + d2], si = sn[s * 32 + d2];
    u32* addr = (u32*)&qkv[(size_t)m * 3072 + col];
    u32 v = *addr;
    float a = bf2f(v & 0xffffu), b = bf2f(v >> 16);
    float na = a * c - b * si;
    float nb = a * si + b * c;
    *addr = (u32)f2bf(na) | ((u32)f2bf(nb) << 16);
    return;
  }
  const int id2 = bid - 20480;                   // ---- V transpose
  const int s0 = (id2 & 31) * 64;
  const int bk = id2 >> 5;                       // b*8 + kvh
  const int b = bk >> 3, kvh = bk & 7;
  const int tx = threadIdx.x & 63, ty = threadIdx.x >> 6;  // ty 0..3
#pragma unroll
  for (int r = 0; r < 16; ++r)
    t[ty + 4 * r][tx] =
        qkv[(size_t)(b * 2048 + s0 + ty + 4 * r) * 3072 + 2560 + kvh * 64 + tx];
  __syncthreads();
#pragma unroll
  for (int r = 0; r < 16; ++r)
    VtG[(size_t)(bk * 64 + ty + 4 * r) * 2048 + s0 + tx] = t[tx][ty + 4 * r];
}

// ---------------------------------------------------------------------------
// 128x128 BK=32 2-phase GEMM: C[M,N] = A[M,K]*Bt[N,K]^T, bf16 or fp32 out.
// Epilogue routes C through the dead staging LDS -> full-line global stores.
template <bool BF16OUT>
__global__ __launch_bounds__(256) void gemm_bt(const u16* __restrict__ A,
                                               const u16* __restrict__ Bt,
                                               void* __restrict__ Cv,
                                               int M, int N, int K, int GX) {
  __shared__ u16 SM[2][2][128 * 32];             // [A/B][buf][tile] = 32 KB
  const int tid = threadIdx.x;
  const int wid = tid >> 6, lane = tid & 63;
  const int l15 = lane & 15, lq = lane >> 4;
  const int wr = wid >> 1, wc = wid & 1;
  const int cpx = gridDim.x >> 3;                 // gridDim.x % 8 == 0
  const int swz = (blockIdx.x & 7) * cpx + (blockIdx.x >> 3);
  const int m0 = (swz / GX) * 128, n0 = (swz % GX) * 128;

  const int srow16 = lane >> 2;
  const int k8 = (lane & 3) * 8;

  auto STAGE = [&](int bb, int kt) {
#pragma unroll
    for (int i = 0; i < 2; ++i) {
      const int r = wid * 2 + i;                  // 16-row region
      const int row = r * 16 + srow16;
      gload_lds16(A + (size_t)(m0 + row) * K + kt + k8, &SM[0][bb][r * 512]);
      gload_lds16(Bt + (size_t)(n0 + row) * K + kt + k8, &SM[1][bb][r * 512]);
    }
  };

  f32x4 acc[4][4] = {};
  STAGE(0, 0);
  __syncthreads();
  int cur = 0;
  for (int kt = 0; kt < K; kt += 32) {
    if (kt + 32 < K) STAGE(cur ^ 1, kt + 32);
    s16x8 af[4], bf[4];
#pragma unroll
    for (int i = 0; i < 4; ++i)
      af[i] = *(const s16x8*)&SM[0][cur][(wr * 64 + i * 16 + l15) * 32 + 8 * lq];
#pragma unroll
    for (int j = 0; j < 4; ++j)
      bf[j] = *(const s16x8*)&SM[1][cur][(wc * 64 + j * 16 + l15) * 32 + 8 * lq];
#pragma unroll
    for (int i = 0; i < 4; ++i)
#pragma unroll
      for (int j = 0; j < 4; ++j)
        acc[i][j] = mfma16(af[i], bf[j], acc[i][j]);
    __syncthreads();                              // drains next-tile loads too
    cur ^= 1;
  }

  if constexpr (BF16OUT) {
    u16* lds = &SM[0][0][0];                      // 16384 u16 = 32 KB
    u16* Cb = (u16*)Cv;
#pragma unroll
    for (int i = 0; i < 4; ++i)
#pragma unroll
      for (int j = 0; j < 4; ++j)
#pragma unroll
        for (int r = 0; r < 4; ++r)
          lds[(wr * 64 + i * 16 + 4 * lq + r) * 128 + wc * 64 + j * 16 + l15] =
              f2bf(acc[i][j][r]);
    __syncthreads();
#pragma unroll
    for (int k = 0; k < 8; ++k) {
      const int rowL = k * 16 + (tid >> 4);
      const int colL = (tid & 15) * 8;
      u16x8 v = *(const u16x8*)&lds[rowL * 128 + colL];
      *(u16x8*)(Cb + (size_t)(m0 + rowL) * N + n0 + colL) = v;
    }
  } else {
    float* lds = (float*)&SM[0][0][0];            // 8192 f32 = 32 KB
    float* Cf = (float*)Cv;
#pragma unroll
    for (int half = 0; half < 2; ++half) {
      if (wc == half) {
#pragma unroll
        for (int i = 0; i < 4; ++i)
#pragma unroll
          for (int j = 0; j < 4; ++j)
#pragma unroll
            for (int r = 0; r < 4; ++r)
              lds[(wr * 64 + i * 16 + 4 * lq + r) * 64 + j * 16 + l15] =
                  acc[i][j][r];
      }
      __syncthreads();
#pragma unroll
      for (int k = 0; k < 8; ++k) {
        const int rowL = k * 16 + (tid >> 4);
        const int colL = (tid & 15) * 4;
        f32x4 v = *(const f32x4*)&lds[rowL * 64 + colL];
        *(f32x4*)(Cf + (size_t)(m0 + rowL) * N + n0 + half * 64 + colL) = v;
      }
      __syncthreads();
    }
  }
}

// ---------------------------------------------------------------------------
// Flash attention: paired q-tiles {15-bx, bx} per block (17 steps constant),
// 8 waves in 2 groups (A: KV[0,qt+1), B: KV[qt+1,2qt+2)), separate LDS
// double-buffers. Static-max softmax (m=0; exp2 ceiling ~2^15, row-sum
// ~2^26 -- safely inside fp32 range), pipelined QK^T (issued right after the
// step barrier so its latency hides under STAGE/loop overhead), per-lane
// row-sum with a single cross-lane merge after the loop (register-neutral).
__global__ __launch_bounds__(512, 4) void attn_kernel(const u16* __restrict__ qkv,
                                                      const u16* __restrict__ VtG,
                                                      u16* __restrict__ aout) {
  constexpr int QSTR = 3072;
  constexpr float SCL = 0.18033688011112042f;    // (1/8) * log2(e)
  const int bx = blockIdx.x;                     // 0..7
  const int bh = blockIdx.y;
  const int b = bh >> 5, h = bh & 31, kvh = h >> 2;
  const int tid = threadIdx.x;
  const int w = tid >> 6, g = w >> 2, wq = w & 3;  // group, wave-in-group
  const int l31 = tid & 31, hh = (tid >> 5) & 1;

  __shared__ u16 KV[2][2][2][4096];              // [group][K/V][buf]
  __shared__ float cml[128];                     // l partials (group B)

  const int u = tid & 255;
  const int srow = u >> 3, sslot = u & 7;
  const int sd8 = (sslot ^ (srow & 7)) * 8;      // pre-swizzled source slot
  const u16* kg = qkv + (size_t)(b * 2048 + srow) * QSTR + 2048 + kvh * 64 + sd8;
  const u16* vg = VtG + (size_t)((b * 8 + kvh) * 64 + srow) * 2048 + sd8;
  const int wg = u >> 6;                         // wave-in-group 0..3
  const int xsw = l31 & 7;                       // read-side row XOR

  auto STAGE = [&](int buf, int t) {             // t = global KV tile index
    const size_t ko = (size_t)t * 64 * QSTR;
    const size_t vo = (size_t)t * 64;
    gload_lds16(kg + ko, &KV[g][0][buf][wg * 512]);
    gload_lds16(kg + ko + (size_t)32 * QSTR, &KV[g][0][buf][2048 + wg * 512]);
    gload_lds16(vg + vo, &KV[g][1][buf][wg * 512]);
    gload_lds16(vg + vo + (size_t)32 * 2048, &KV[g][1][buf][2048 + wg * 512]);
  };

  float* cO = (float*)&KV[1][0][0][0];           // 8192 f32 = 32 KB, 64 slots

  auto process = [&](int qt) {
    const int h1 = qt + 1;                       // steps per group
    const int q_abs = qt * 128 + wq * 32 + l31;  // lane's q row (both groups)
    const u16* qrow = qkv + (size_t)(b * 2048 + q_abs) * QSTR + h * 64;
    s16x8 qf[4];
#pragma unroll
    for (int s = 0; s < 4; ++s) qf[s] = *(const s16x8*)(qrow + 16 * s + 8 * hh);

    f32x16 o0 = {}, o1 = {};                     // O^T partial: d 0..31/32..63
    float lrun = 0.f;                            // per-lane partial (hh half)
    f32x16 a0, a1;                               // current tile scores

    auto qkt = [&](const u16* Kb) {
      a0 = (f32x16){}; a1 = (f32x16){};
      __builtin_amdgcn_s_setprio(1);
#pragma unroll
      for (int s4 = 0; s4 < 4; ++s4) {
        const int cc = ((2 * s4 + hh) ^ xsw) * 8;
        s16x8 k0 = *(const s16x8*)(Kb + l31 * 64 + cc);
        s16x8 k1 = *(const s16x8*)(Kb + (32 + l31) * 64 + cc);
        a0 = mfma32(k0, qf[s4], a0);
        a1 = mfma32(k1, qf[s4], a1);
      }
      __builtin_amdgcn_s_setprio(0);
    };

    STAGE(0, g * h1);
    __syncthreads();                             // buf0 ready
    qkt(&KV[g][0][0][0]);                        // scores for step 0

    for (int s = 0; s < h1; ++s) {
      if (s + 1 < h1) STAGE((s + 1) & 1, g * h1 + s + 1);
      const int kv0 = (g * h1 + s) * 64;

      // ---- causal mask (raw domain)
      if (kv0 + 63 > qt * 128 + wq * 32) {
#pragma unroll
        for (int r = 0; r < 16; ++r) {
          const int kva = kv0 + (r & 3) + 8 * (r >> 2) + 4 * hh;
          if (kva > q_abs) a0[r] = -3e38f;
          if (kva + 32 > q_abs) a1[r] = -3e38f;
        }
      }

      // ---- static-max softmax: p = exp2(score*SCL), per-lane row sum
      float sum = 0.f;
#pragma unroll
      for (int r = 0; r < 16; ++r) {
        a0[r] = fexp2(a0[r] * SCL);
        a1[r] = fexp2(a1[r] * SCL);
        sum += a0[r] + a1[r];
      }
      lrun += sum;                               // cross-lane merge deferred

      // ---- pack P^T B-fragments (cvt_pk + permlane32_swap)
      s16x8 pf[4];
#pragma unroll
      for (int s4 = 0; s4 < 4; ++s4) {
        const f32x16& ps = (s4 & 2) ? a1 : a0;
        const int g4 = (s4 & 1) * 8;
        u32 x  = cvtpk(ps[g4 + 0], ps[g4 + 1]);
        u32 x2 = cvtpk(ps[g4 + 2], ps[g4 + 3]);
        u32 y  = cvtpk(ps[g4 + 4], ps[g4 + 5]);
        u32 y2 = cvtpk(ps[g4 + 6], ps[g4 + 7]);
        asm("v_permlane32_swap_b32 %0, %1" : "+v"(x), "+v"(y));
        asm("v_permlane32_swap_b32 %0, %1" : "+v"(x2), "+v"(y2));
        u32x4 fr = {x, x2, y, y2};
        pf[s4] = __builtin_bit_cast(s16x8, fr);
      }

      // ---- PV: O^T += V^T * P^T
      const u16* Vb = &KV[g][1][s & 1][0];
      __builtin_amdgcn_s_setprio(1);
#pragma unroll
      for (int s4 = 0; s4 < 4; ++s4) {
        const int cc = ((2 * s4 + hh) ^ xsw) * 8;
        s16x8 v0f = *(const s16x8*)(Vb + l31 * 64 + cc);
        s16x8 v1f = *(const s16x8*)(Vb + (32 + l31) * 64 + cc);
        o0 = mfma32(v0f, pf[s4], o0);
        o1 = mfma32(v1f, pf[s4], o1);
      }
      __builtin_amdgcn_s_setprio(0);

      __syncthreads();                           // drains s+1 loads; frees bufs
      if (s + 1 < h1) qkt(&KV[g][0][(s + 1) & 1][0]);   // pipelined next QK^T
    }

    lrun += __shfl_xor(lrun, 32);                // single cross-lane merge

    // ---- combine (shared m=0 basis): B writes partials; A merges.
    const int idx = wq * 32 + l31;
    if (g == 1) {
#pragma unroll
      for (int r = 0; r < 16; ++r) {
        cO[(hh * 16 + r) * 128 + idx] = o0[r];
        cO[(32 + hh * 16 + r) * 128 + idx] = o1[r];
      }
      if (hh == 0) cml[idx] = lrun;
    }
    __syncthreads();
    if (g == 0) {
      const float inv = 1.f / (lrun + cml[idx]);
      u16* ob = aout + (size_t)(b * 2048 + q_abs) * 2048 + h * 64;
#pragma unroll
      for (int gg = 0; gg < 4; ++gg) {
        u16x4 w0, w1;
#pragma unroll
        for (int j = 0; j < 4; ++j) {
          const int r = 4 * gg + j;
          w0[j] = f2bf((o0[r] + cO[(hh * 16 + r) * 128 + idx]) * inv);
          w1[j] = f2bf((o1[r] + cO[(32 + hh * 16 + r) * 128 + idx]) * inv);
        }
        *(u16x4*)(ob + 8 * gg + 4 * hh) = w0;
        *(u16x4*)(ob + 32 + 8 * gg + 4 * hh) = w1;
      }
    }
    __syncthreads();                             // scratch freed before reuse
  };

  process(15 - bx);   // heavy q-tile: 16-bx steps
  process(bx);        // light q-tile: bx+1 steps -> 17 steps per block
}

// ---------------------------------------------------------------------------
extern "C" void kernel_launch(void* const* d_in, const int* in_sizes, int n_in,
                              void* d_out, int out_size, void* d_ws, size_t ws_size,
                              hipStream_t stream) {
  const float* x    = (const float*)d_in[0];
  const float* wq   = (const float*)d_in[1];
  const float* wk   = (const float*)d_in[2];
  const float* wv   = (const float*)d_in[3];
  const float* wo   = (const float*)d_in[4];
  const float* cosT = (const float*)d_in[5];
  const float* sinT = (const float*)d_in[6];
  float* out = (float*)d_out;

  const size_t SZ_XB   = (size_t)4096 * 2048 * 2;
  const size_t SZ_WQKV = (size_t)3072 * 2048 * 2;
  const size_t SZ_WO   = (size_t)2048 * 2048 * 2;
  const size_t SZ_QKV  = (size_t)4096 * 3072 * 2;
  const size_t SZ_ATT  = (size_t)4096 * 2048 * 2;
  if (ws_size < SZ_XB + SZ_WQKV + SZ_WO + SZ_QKV + SZ_ATT) return;

  char* p = (char*)d_ws;
  u16* xb    = (u16*)p; p += SZ_XB;
  u16* wqkvT = (u16*)p; p += SZ_WQKV;
  u16* woT   = (u16*)p; p += SZ_WO;
  u16* qkv   = (u16*)p; p += SZ_QKV;
  u16* attn  = (u16*)p; p += SZ_ATT;
  u16* VtG   = xb;   // xb is dead after the QKV GEMM; ropevt runs after it

  prep_kernel<<<18432, 256, 0, stream>>>(x, wq, wk, wv, wo, xb, wqkvT, woT);
  gemm_bt<true><<<768, 256, 0, stream>>>(xb, wqkvT, qkv, 4096, 3072, 2048, 24);
  ropevt_kernel<<<20992, 256, 0, stream>>>(qkv, cosT, sinT, VtG);
  attn_kernel<<<dim3(8, 64), 512, 0, stream>>>(qkv, VtG, attn);
  gemm_bt<false><<<512, 256, 0, stream>>>(attn, woT, out, 4096, 2048, 2048, 16);
}

// Round 20
// 190.235 us; speedup vs baseline: 1.3200x; 1.0278x over previous
//
#include <hip/hip_runtime.h>

// ---------------------------------------------------------------------------
// Attention block (B=2, S=2048, DIM=2048, H=32, KVH=8, HD=64, causal, RoPE)
// prep (cvt x + 4 weight transposes) ; QKV GEMM (128^2 2-phase, LDS-shuffled
// full-line C-store) ; rope+vt ; flash attention (paired q-tiles, 8 waves,
// KV-split, static-max softmax, pipelined QK^T) ; out GEMM (fp32) -> d_out
// ---------------------------------------------------------------------------

using u16   = unsigned short;
using u32   = unsigned int;
using f32x4 = __attribute__((ext_vector_type(4))) float;
using f32x16= __attribute__((ext_vector_type(16))) float;
using s16x8 = __attribute__((ext_vector_type(8))) short;
using b16x8 = __attribute__((ext_vector_type(8))) __bf16;
using u16x4 = __attribute__((ext_vector_type(4))) unsigned short;
using u16x8 = __attribute__((ext_vector_type(8))) unsigned short;
using u32x4 = __attribute__((ext_vector_type(4))) u32;

__device__ __forceinline__ u16 f2bf(float f) {
  u32 u = __builtin_bit_cast(u32, f);
  u = (u + 0x7fffu + ((u >> 16) & 1u)) >> 16;   // round-to-nearest-even
  return (u16)u;
}
__device__ __forceinline__ float bf2f(u32 lo16) {
  return __builtin_bit_cast(float, lo16 << 16);
}

__device__ __forceinline__ f32x4 mfma16(s16x8 a, s16x8 b, f32x4 c) {
  return __builtin_amdgcn_mfma_f32_16x16x32_bf16(
      __builtin_bit_cast(b16x8, a), __builtin_bit_cast(b16x8, b), c, 0, 0, 0);
}
__device__ __forceinline__ f32x16 mfma32(s16x8 a, s16x8 b, f32x16 c) {
  return __builtin_amdgcn_mfma_f32_32x32x16_bf16(
      __builtin_bit_cast(b16x8, a), __builtin_bit_cast(b16x8, b), c, 0, 0, 0);
}

__device__ __forceinline__ void gload_lds16(const void* g, void* l) {
  __builtin_amdgcn_global_load_lds(
      (const __attribute__((address_space(1))) void*)g,
      (__attribute__((address_space(3))) void*)l, 16, 0, 0);
}

__device__ __forceinline__ u32 cvtpk(float lo, float hi) {
  u32 r; asm("v_cvt_pk_bf16_f32 %0, %1, %2" : "=v"(r) : "v"(lo), "v"(hi));
  return r;
}

__device__ __forceinline__ float fexp2(float x) {
#if __has_builtin(__builtin_amdgcn_exp2f)
  return __builtin_amdgcn_exp2f(x);
#else
  return exp2f(x);
#endif
}

// ---------------------------------------------------------------------------
// prep: job-merged {cvt x -> bf16} + {transpose-cvt wq, wk, wv, wo}.
__global__ __launch_bounds__(256) void prep_kernel(
    const float* __restrict__ x,  const float* __restrict__ wq,
    const float* __restrict__ wk, const float* __restrict__ wv,
    const float* __restrict__ wo, u16* __restrict__ xb,
    u16* __restrict__ wqkvT, u16* __restrict__ woT) {
  __shared__ float t[32][33];
  int bid = blockIdx.x;
  if (bid < 8192) {                              // ---- cvt x (float4/thread)
    const int i = bid * 256 + threadIdx.x;       // < 2097152
    f32x4 v = *(const f32x4*)(x + (size_t)i * 4);
    u16x4 r;
#pragma unroll
    for (int j = 0; j < 4; ++j) r[j] = f2bf(v[j]);
    *(u16x4*)(xb + (size_t)i * 4) = r;
    return;
  }
  bid -= 8192;
  const float* src;  u16* dst;  int N, gx;
  if (bid < 4096)      { src = wq; dst = wqkvT;                          N = 2048; gx = 64; }
  else if (bid < 5120) { bid -= 4096; src = wk; dst = wqkvT + (size_t)2048 * 2048; N = 512; gx = 16; }
  else if (bid < 6144) { bid -= 5120; src = wv; dst = wqkvT + (size_t)2560 * 2048; N = 512; gx = 16; }
  else                 { bid -= 6144; src = wo; dst = woT;               N = 2048; gx = 64; }
  const int n0 = (bid % gx) * 32, k0 = (bid / gx) * 32;
  const int tx = threadIdx.x & 31, ty = threadIdx.x >> 5;
#pragma unroll
  for (int r = 0; r < 4; ++r)
    t[ty + 8 * r][tx] = src[(size_t)(k0 + ty + 8 * r) * N + n0 + tx];
  __syncthreads();
#pragma unroll
  for (int r = 0; r < 4; ++r)
    dst[(size_t)(n0 + ty + 8 * r) * 2048 + k0 + tx] = f2bf(t[tx][ty + 8 * r]);
}

// ---------------------------------------------------------------------------
// ropevt: job-merged {RoPE in-place on q,k cols} + {V transpose to VtG}.
__global__ __launch_bounds__(256) void ropevt_kernel(u16* __restrict__ qkv,
                                                     const float* __restrict__ cs,
                                                     const float* __restrict__ sn,
                                                     u16* __restrict__ VtG) {
  __shared__ u16 t[64][65];
  const int bid = blockIdx.x;
  if (bid < 20480) {                             // ---- RoPE
    const int m = bid & 4095;
    const int p = (bid >> 12) * 256 + threadIdx.x;   // 0..1279
    const int s = m & 2047;
    int col, d2;
    if (p < 1024) { col = 2 * p; d2 = p & 31; }
    else { int pk = p - 1024; col = 2048 + 2 * pk; d2 = pk & 31; }
    const float c = cs[s * 32 + d2], si = sn[s * 32 + d2];
    u32* addr = (u32*)&qkv[(size_t)m * 3072 + col];
    u32 v = *addr;
    float a = bf2f(v & 0xffffu), b = bf2f(v >> 16);
    float na = a * c - b * si;
    float nb = a * si + b * c;
    *addr = (u32)f2bf(na) | ((u32)f2bf(nb) << 16);
    return;
  }
  const int id2 = bid - 20480;                   // ---- V transpose
  const int s0 = (id2 & 31) * 64;
  const int bk = id2 >> 5;                       // b*8 + kvh
  const int b = bk >> 3, kvh = bk & 7;
  const int tx = threadIdx.x & 63, ty = threadIdx.x >> 6;  // ty 0..3
#pragma unroll
  for (int r = 0; r < 16; ++r)
    t[ty + 4 * r][tx] =
        qkv[(size_t)(b * 2048 + s0 + ty + 4 * r) * 3072 + 2560 + kvh * 64 + tx];
  __syncthreads();
#pragma unroll
  for (int r = 0; r < 16; ++r)
    VtG[(size_t)(bk * 64 + ty + 4 * r) * 2048 + s0 + tx] = t[tx][ty + 4 * r];
}

// ---------------------------------------------------------------------------
// 128x128 BK=32 2-phase GEMM: C[M,N] = A[M,K]*Bt[N,K]^T, bf16 or fp32 out.
// Epilogue routes C through the dead staging LDS -> full-line global stores.
template <bool BF16OUT>
__global__ __launch_bounds__(256) void gemm_bt(const u16* __restrict__ A,
                                               const u16* __restrict__ Bt,
                                               void* __restrict__ Cv,
                                               int M, int N, int K, int GX) {
  __shared__ u16 SM[2][2][128 * 32];             // [A/B][buf][tile] = 32 KB
  const int tid = threadIdx.x;
  const int wid = tid >> 6, lane = tid & 63;
  const int l15 = lane & 15, lq = lane >> 4;
  const int wr = wid >> 1, wc = wid & 1;
  const int cpx = gridDim.x >> 3;                 // gridDim.x % 8 == 0
  const int swz = (blockIdx.x & 7) * cpx + (blockIdx.x >> 3);
  const int m0 = (swz / GX) * 128, n0 = (swz % GX) * 128;

  const int srow16 = lane >> 2;
  const int k8 = (lane & 3) * 8;

  auto STAGE = [&](int bb, int kt) {
#pragma unroll
    for (int i = 0; i < 2; ++i) {
      const int r = wid * 2 + i;                  // 16-row region
      const int row = r * 16 + srow16;
      gload_lds16(A + (size_t)(m0 + row) * K + kt + k8, &SM[0][bb][r * 512]);
      gload_lds16(Bt + (size_t)(n0 + row) * K + kt + k8, &SM[1][bb][r * 512]);
    }
  };

  f32x4 acc[4][4] = {};
  STAGE(0, 0);
  __syncthreads();
  int cur = 0;
  for (int kt = 0; kt < K; kt += 32) {
    if (kt + 32 < K) STAGE(cur ^ 1, kt + 32);
    s16x8 af[4], bf[4];
#pragma unroll
    for (int i = 0; i < 4; ++i)
      af[i] = *(const s16x8*)&SM[0][cur][(wr * 64 + i * 16 + l15) * 32 + 8 * lq];
#pragma unroll
    for (int j = 0; j < 4; ++j)
      bf[j] = *(const s16x8*)&SM[1][cur][(wc * 64 + j * 16 + l15) * 32 + 8 * lq];
#pragma unroll
    for (int i = 0; i < 4; ++i)
#pragma unroll
      for (int j = 0; j < 4; ++j)
        acc[i][j] = mfma16(af[i], bf[j], acc[i][j]);
    __syncthreads();                              // drains next-tile loads too
    cur ^= 1;
  }

  if constexpr (BF16OUT) {
    u16* lds = &SM[0][0][0];                      // 16384 u16 = 32 KB
    u16* Cb = (u16*)Cv;
#pragma unroll
    for (int i = 0; i < 4; ++i)
#pragma unroll
      for (int j = 0; j < 4; ++j)
#pragma unroll
        for (int r = 0; r < 4; ++r)
          lds[(wr * 64 + i * 16 + 4 * lq + r) * 128 + wc * 64 + j * 16 + l15] =
              f2bf(acc[i][j][r]);
    __syncthreads();
#pragma unroll
    for (int k = 0; k < 8; ++k) {
      const int rowL = k * 16 + (tid >> 4);
      const int colL = (tid & 15) * 8;
      u16x8 v = *(const u16x8*)&lds[rowL * 128 + colL];
      *(u16x8*)(Cb + (size_t)(m0 + rowL) * N + n0 + colL) = v;
    }
  } else {
    float* lds = (float*)&SM[0][0][0];            // 8192 f32 = 32 KB
    float* Cf = (float*)Cv;
#pragma unroll
    for (int half = 0; half < 2; ++half) {
      if (wc == half) {
#pragma unroll
        for (int i = 0; i < 4; ++i)
#pragma unroll
          for (int j = 0; j < 4; ++j)
#pragma unroll
            for (int r = 0; r < 4; ++r)
              lds[(wr * 64 + i * 16 + 4 * lq + r) * 64 + j * 16 + l15] =
                  acc[i][j][r];
      }
      __syncthreads();
#pragma unroll
      for (int k = 0; k < 8; ++k) {
        const int rowL = k * 16 + (tid >> 4);
        const int colL = (tid & 15) * 4;
        f32x4 v = *(const f32x4*)&lds[rowL * 64 + colL];
        *(f32x4*)(Cf + (size_t)(m0 + rowL) * N + n0 + half * 64 + colL) = v;
      }
      __syncthreads();
    }
  }
}

// ---------------------------------------------------------------------------
// Flash attention: paired q-tiles {15-bx, bx} per block (17 steps constant),
// 8 waves in 2 groups (A: KV[0,qt+1), B: KV[qt+1,2qt+2)), separate LDS
// double-buffers. STATIC-MAX softmax (m=0; exp2 ceiling ~2^15, row-sum
// ~2^26 -- safely inside fp32/bf16 range, so no running max / rescale) and
// PIPELINED QK^T: qkt(s+1) issues after the step-s barrier, so its MFMA
// latency is hidden behind the next iteration's STAGE + loop overhead and
// softmax never stalls on fresh MFMA results. hh-aware LDS combine.
__global__ __launch_bounds__(512, 4) void attn_kernel(const u16* __restrict__ qkv,
                                                      const u16* __restrict__ VtG,
                                                      u16* __restrict__ aout) {
  constexpr int QSTR = 3072;
  constexpr float SCL = 0.18033688011112042f;    // (1/8) * log2(e)
  const int bx = blockIdx.x;                     // 0..7
  const int bh = blockIdx.y;
  const int b = bh >> 5, h = bh & 31, kvh = h >> 2;
  const int tid = threadIdx.x;
  const int w = tid >> 6, g = w >> 2, wq = w & 3;  // group, wave-in-group
  const int l31 = tid & 31, hh = (tid >> 5) & 1;

  __shared__ u16 KV[2][2][2][4096];              // [group][K/V][buf]
  __shared__ float cml[128];                     // l partials (group B)

  const int u = tid & 255;
  const int srow = u >> 3, sslot = u & 7;
  const int sd8 = (sslot ^ (srow & 7)) * 8;      // pre-swizzled source slot
  const u16* kg = qkv + (size_t)(b * 2048 + srow) * QSTR + 2048 + kvh * 64 + sd8;
  const u16* vg = VtG + (size_t)((b * 8 + kvh) * 64 + srow) * 2048 + sd8;
  const int wg = u >> 6;                         // wave-in-group 0..3
  const int xsw = l31 & 7;                       // read-side row XOR

  auto STAGE = [&](int buf, int t) {             // t = global KV tile index
    const size_t ko = (size_t)t * 64 * QSTR;
    const size_t vo = (size_t)t * 64;
    gload_lds16(kg + ko, &KV[g][0][buf][wg * 512]);
    gload_lds16(kg + ko + (size_t)32 * QSTR, &KV[g][0][buf][2048 + wg * 512]);
    gload_lds16(vg + vo, &KV[g][1][buf][wg * 512]);
    gload_lds16(vg + vo + (size_t)32 * 2048, &KV[g][1][buf][2048 + wg * 512]);
  };

  float* cO = (float*)&KV[1][0][0][0];           // 8192 f32 = 32 KB, 64 slots

  auto process = [&](int qt) {
    const int h1 = qt + 1;                       // steps per group
    const int q_abs = qt * 128 + wq * 32 + l31;  // lane's q row (both groups)
    const u16* qrow = qkv + (size_t)(b * 2048 + q_abs) * QSTR + h * 64;
    s16x8 qf[4];
#pragma unroll
    for (int s = 0; s < 4; ++s) qf[s] = *(const s16x8*)(qrow + 16 * s + 8 * hh);

    f32x16 o0 = {}, o1 = {};                     // O^T partial: d 0..31/32..63
    float lrun = 0.f;
    f32x16 a0, a1;                               // current tile scores

    auto qkt = [&](const u16* Kb) {
      a0 = (f32x16){}; a1 = (f32x16){};
      __builtin_amdgcn_s_setprio(1);
#pragma unroll
      for (int s4 = 0; s4 < 4; ++s4) {
        const int cc = ((2 * s4 + hh) ^ xsw) * 8;
        s16x8 k0 = *(const s16x8*)(Kb + l31 * 64 + cc);
        s16x8 k1 = *(const s16x8*)(Kb + (32 + l31) * 64 + cc);
        a0 = mfma32(k0, qf[s4], a0);
        a1 = mfma32(k1, qf[s4], a1);
      }
      __builtin_amdgcn_s_setprio(0);
    };

    STAGE(0, g * h1);
    __syncthreads();                             // buf0 ready
    qkt(&KV[g][0][0][0]);                        // scores for step 0

    for (int s = 0; s < h1; ++s) {
      if (s + 1 < h1) STAGE((s + 1) & 1, g * h1 + s + 1);
      const int kv0 = (g * h1 + s) * 64;

      // ---- causal mask (raw domain)
      if (kv0 + 63 > qt * 128 + wq * 32) {
#pragma unroll
        for (int r = 0; r < 16; ++r) {
          const int kva = kv0 + (r & 3) + 8 * (r >> 2) + 4 * hh;
          if (kva > q_abs) a0[r] = -3e38f;
          if (kva + 32 > q_abs) a1[r] = -3e38f;
        }
      }

      // ---- static-max softmax: p = exp2(score*SCL), row sum
      float sum = 0.f;
#pragma unroll
      for (int r = 0; r < 16; ++r) {
        a0[r] = fexp2(a0[r] * SCL);
        a1[r] = fexp2(a1[r] * SCL);
        sum += a0[r] + a1[r];
      }
      sum += __shfl_xor(sum, 32);
      lrun += sum;

      // ---- pack P^T B-fragments (cvt_pk + permlane32_swap)
      s16x8 pf[4];
#pragma unroll
      for (int s4 = 0; s4 < 4; ++s4) {
        const f32x16& ps = (s4 & 2) ? a1 : a0;
        const int g4 = (s4 & 1) * 8;
        u32 x  = cvtpk(ps[g4 + 0], ps[g4 + 1]);
        u32 x2 = cvtpk(ps[g4 + 2], ps[g4 + 3]);
        u32 y  = cvtpk(ps[g4 + 4], ps[g4 + 5]);
        u32 y2 = cvtpk(ps[g4 + 6], ps[g4 + 7]);
        asm("v_permlane32_swap_b32 %0, %1" : "+v"(x), "+v"(y));
        asm("v_permlane32_swap_b32 %0, %1" : "+v"(x2), "+v"(y2));
        u32x4 fr = {x, x2, y, y2};
        pf[s4] = __builtin_bit_cast(s16x8, fr);
      }

      // ---- PV: O^T += V^T * P^T
      const u16* Vb = &KV[g][1][s & 1][0];
      __builtin_amdgcn_s_setprio(1);
#pragma unroll
      for (int s4 = 0; s4 < 4; ++s4) {
        const int cc = ((2 * s4 + hh) ^ xsw) * 8;
        s16x8 v0f = *(const s16x8*)(Vb + l31 * 64 + cc);
        s16x8 v1f = *(const s16x8*)(Vb + (32 + l31) * 64 + cc);
        o0 = mfma32(v0f, pf[s4], o0);
        o1 = mfma32(v1f, pf[s4], o1);
      }
      __builtin_amdgcn_s_setprio(0);

      __syncthreads();                           // drains s+1 loads; frees bufs
      if (s + 1 < h1) qkt(&KV[g][0][(s + 1) & 1][0]);   // pipelined next QK^T
    }

    // ---- combine (shared m=0 basis): B writes partials; A merges.
    const int idx = wq * 32 + l31;
    if (g == 1) {
#pragma unroll
      for (int r = 0; r < 16; ++r) {
        cO[(hh * 16 + r) * 128 + idx] = o0[r];
        cO[(32 + hh * 16 + r) * 128 + idx] = o1[r];
      }
      if (hh == 0) cml[idx] = lrun;
    }
    __syncthreads();
    if (g == 0) {
      const float inv = 1.f / (lrun + cml[idx]);
      u16* ob = aout + (size_t)(b * 2048 + q_abs) * 2048 + h * 64;
#pragma unroll
      for (int gg = 0; gg < 4; ++gg) {
        u16x4 w0, w1;
#pragma unroll
        for (int j = 0; j < 4; ++j) {
          const int r = 4 * gg + j;
          w0[j] = f2bf((o0[r] + cO[(hh * 16 + r) * 128 + idx]) * inv);
          w1[j] = f2bf((o1[r] + cO[(32 + hh * 16 + r) * 128 + idx]) * inv);
        }
        *(u16x4*)(ob + 8 * gg + 4 * hh) = w0;
        *(u16x4*)(ob + 32 + 8 * gg + 4 * hh) = w1;
      }
    }
    __syncthreads();                             // scratch freed before reuse
  };

  process(15 - bx);   // heavy q-tile: 16-bx steps
  process(bx);        // light q-tile: bx+1 steps -> 17 steps per block
}

// ---------------------------------------------------------------------------
extern "C" void kernel_launch(void* const* d_in, const int* in_sizes, int n_in,
                              void* d_out, int out_size, void* d_ws, size_t ws_size,
                              hipStream_t stream) {
  const float* x    = (const float*)d_in[0];
  const float* wq   = (const float*)d_in[1];
  const float* wk   = (const float*)d_in[2];
  const float* wv   = (const float*)d_in[3];
  const float* wo   = (const float*)d_in[4];
  const float* cosT = (const float*)d_in[5];
  const float* sinT = (const float*)d_in[6];
  float* out = (float*)d_out;

  const size_t SZ_XB   = (size_t)4096 * 2048 * 2;
  const size_t SZ_WQKV = (size_t)3072 * 2048 * 2;
  const size_t SZ_WO   = (size_t)2048 * 2048 * 2;
  const size_t SZ_QKV  = (size_t)4096 * 3072 * 2;
  const size_t SZ_ATT  = (size_t)4096 * 2048 * 2;
  if (ws_size < SZ_XB + SZ_WQKV + SZ_WO + SZ_QKV + SZ_ATT) return;

  char* p = (char*)d_ws;
  u16* xb    = (u16*)p; p += SZ_XB;
  u16* wqkvT = (u16*)p; p += SZ_WQKV;
  u16* woT   = (u16*)p; p += SZ_WO;
  u16* qkv   = (u16*)p; p += SZ_QKV;
  u16* attn  = (u16*)p; p += SZ_ATT;
  u16* VtG   = xb;   // xb is dead after the QKV GEMM; ropevt runs after it

  prep_kernel<<<18432, 256, 0, stream>>>(x, wq, wk, wv, wo, xb, wqkvT, woT);
  gemm_bt<true><<<768, 256, 0, stream>>>(xb, wqkvT, qkv, 4096, 3072, 2048, 24);
  ropevt_kernel<<<20992, 256, 0, stream>>>(qkv, cosT, sinT, VtG);
  attn_kernel<<<dim3(8, 64), 512, 0, stream>>>(qkv, VtG, attn);
  gemm_bt<false><<<512, 256, 0, stream>>>(attn, woT, out, 4096, 2048, 2048, 16);
}